// Round 16
// baseline (241.561 us; speedup 1.0000x reference)
//
#include <hip/hip_runtime.h>

// GALA graph autoencoder on MI355X — round 16: one-edge-walk-per-thread staging.
// Staging re-tiled in k-PAIRS (16 f16 = 32B per edge per thread): for DIN=64 kernels
// items == threads, so each thread runs exactly ONE dependent-chain edge walk (r15 ran
// two sequential walks per thread); each batch-4 step issues 8 independent 16B loads.
// Also: dinv/offs computation fused into place_kernel (one fewer launch).
// Rest unchanged (r15): degree counting-sort relabel -> slot space; weightless algebra
// prop = dinv ⊙ (A^T (dinv ⊙ h)); propagation fused into consuming GEMM's A-staging;
// f16 intermediates; A_f16 x (W_hi+W_lo) f16 MFMA, LDS-staged W in KC=32 chunks;
// closed-form CSR offsets from degree histogram.

static inline int ceil_div(int a, int b) { return (a + b - 1) / b; }

#define SCAN_BLK 256
#define NBINS 128

typedef _Float16 f16;
typedef _Float16 f16x8 __attribute__((ext_vector_type(8)));
typedef float f32x4 __attribute__((ext_vector_type(4)));

// ---------------- zero fill ----------------

__global__ void zero_kernel(int* __restrict__ p, int n) {
    int i = blockIdx.x * blockDim.x + threadIdx.x;
    if (i < n) p[i] = 0;
}

// ---------------- degree ----------------

__global__ void deg_kernel(const int* __restrict__ col, int* __restrict__ deg, int E) {
    int e = blockIdx.x * blockDim.x + threadIdx.x;
    if (e < E) atomicAdd(&deg[col[e]], 1);
}

// ---------------- counting sort by degree (block-aggregated, deterministic) ----------------

__global__ void hist_kernel(const int* __restrict__ deg, int* __restrict__ blockhist, int n) {
    __shared__ int lh[NBINS];
    if (threadIdx.x < NBINS) lh[threadIdx.x] = 0;
    __syncthreads();
    int i = blockIdx.x * SCAN_BLK + threadIdx.x;
    if (i < n) {
        int d = deg[i]; if (d >= NBINS) d = NBINS - 1;
        atomicAdd(&lh[d], 1);
    }
    __syncthreads();
    if (threadIdx.x < NBINS) blockhist[blockIdx.x * NBINS + threadIdx.x] = lh[threadIdx.x];
}

__global__ void binscan_kernel(int* __restrict__ blockhist, int* __restrict__ bintot, int nb) {
    __shared__ int s[512];
    int bin = blockIdx.x, t = threadIdx.x;
    int v = (t < nb) ? blockhist[t * NBINS + bin] : 0;
    s[t] = v;
    __syncthreads();
    for (int st = 1; st < 512; st <<= 1) {
        int a = (t >= st) ? s[t - st] : 0;
        __syncthreads();
        s[t] += a;
        __syncthreads();
    }
    if (t < nb) blockhist[t * NBINS + bin] = s[t] - v;
    if (t == 0) bintot[bin] = s[511];
}

// 1 block, NBINS threads: binbase = exclscan(bintot); edgebase = exclscan(d*bintot[d])
__global__ void base_scan_kernel(const int* __restrict__ bintot, int* __restrict__ binbase,
                                 int* __restrict__ edgebase) {
    __shared__ int s[NBINS], se[NBINS];
    int t = threadIdx.x;
    int v = bintot[t];
    int ve = v * t;
    s[t] = v; se[t] = ve;
    __syncthreads();
    for (int st = 1; st < NBINS; st <<= 1) {
        int a = (t >= st) ? s[t - st] : 0;
        int ae = (t >= st) ? se[t - st] : 0;
        __syncthreads();
        s[t] += a; se[t] += ae;
        __syncthreads();
    }
    binbase[t] = s[t] - v;
    edgebase[t] = se[t] - ve;
}

// placement + permuted dinv + closed-form CSR offsets (fused)
__global__ void place_kernel(const int* __restrict__ deg, const int* __restrict__ blockhist,
                             const int* __restrict__ binbase, const int* __restrict__ edgebase,
                             int* __restrict__ order, int* __restrict__ slotof,
                             float* __restrict__ dinv_s, float* __restrict__ dinv_h,
                             int* __restrict__ offs, int* __restrict__ cursor, int n, int E) {
    __shared__ int lh[NBINS];
    if (threadIdx.x < NBINS) lh[threadIdx.x] = 0;
    __syncthreads();
    int i = blockIdx.x * SCAN_BLK + threadIdx.x;
    if (i < n) {
        int dd = deg[i];
        int b = dd < NBINS ? dd : NBINS - 1;
        int r = atomicAdd(&lh[b], 1);
        int slot = binbase[b] + blockhist[blockIdx.x * NBINS + b] + r;
        order[slot] = i;
        slotof[i] = slot;
        float d = (float)dd;
        dinv_s[slot] = rsqrtf(d + 1.0f);   // smooth: indeg + 1
        dinv_h[slot] = rsqrtf(d + 2.0f);   // sharp:  indeg + 2
        int o = edgebase[dd] + dd * (slot - binbase[dd]);
        offs[slot] = o;
        cursor[slot] = o;
        if (i == 0) offs[n] = E;
    }
}

__global__ void csr_fill_kernel(const int* __restrict__ row, const int* __restrict__ col,
                                const int* __restrict__ slotof, int* __restrict__ cursor,
                                int* __restrict__ src, int E) {
    int e = blockIdx.x * blockDim.x + threadIdx.x;
    if (e >= E) return;
    int cs = slotof[col[e]];
    int p = atomicAdd(&cursor[cs], 1);
    src[p] = slotof[row[e]];
}

// ---------------- W pre-transpose + split (f32 [DIN][DOUT] -> f16 hi/lo [DOUT][DIN]) ----------------

struct WPtrs { const float* p[6]; };

__global__ void wsplit_kernel(WPtrs wp, f16* __restrict__ wt_hi, f16* __restrict__ wt_lo) {
    const int din[6]  = {128, 64, 32, 16, 32, 64};
    const int dout[6] = {64, 32, 16, 32, 64, 128};
    const int off[6]  = {0, 8192, 10240, 10752, 11264, 13312};
    int t = blockIdx.x * blockDim.x + threadIdx.x;
    if (t >= 21504) return;
    int l = 0;
    while (l < 5 && t >= off[l + 1]) ++l;
    int idx = t - off[l];
    int c = idx / din[l], k = idx - c * din[l];
    float a = wp.p[l][k * dout[l] + c];
    f16 hi = (f16)a;
    f16 lo = (f16)(a - (float)hi);
    wt_hi[t] = hi;
    wt_lo[t] = lo;
}

// ---------------- fused gather + f16 MFMA GEMM ----------------
// A staged full-DIN in k-PAIR units (one 32B slice per edge per thread -> exactly one
// edge walk per thread at DIN=64); W staged in LDS per KC=32 chunk. Staging modes:
//   PLAIN:      v = Af32[perm(row)]
//   SMOOTH:     v = relu( gdinv[r]*(Σ u[src] + u[r]) + gbias )
//   SHARP:      v = gdinv[r]*(2*u[r] - Σ u[src])
//   SHARP_RELU: same as SHARP, relu applied to gathered values
// C = A_f16 @ (W_hi + W_lo), 2 MFMA passes. Epilogue: bias/relu/scale; f16 or f32 out.

#define M_PLAIN 0
#define M_SMOOTH 1
#define M_SHARP 2
#define M_SHARP_RELU 3

template <int DIN, int DOUT, int WAVES, int MODE, bool ADD_BIAS, bool RELU_OUT,
          bool SCALE_ROW, bool IN_PERM, bool OUT_PERM, bool OUT_F32>
__global__ __launch_bounds__(WAVES * 64) void gemm_fused(
        const float* __restrict__ Af, const f16* __restrict__ U,
        const f16* __restrict__ Wth, const f16* __restrict__ Wtl,
        const float* __restrict__ gbias, const float* __restrict__ gdinv,
        const int* __restrict__ offs, const int* __restrict__ srcv,
        const float* __restrict__ bias, const float* __restrict__ rs,
        const int* __restrict__ map, float* __restrict__ outf,
        f16* __restrict__ outh, int n) {
    constexpr int THREADS = WAVES * 64;
    constexpr int BM   = WAVES * 16;               // rows per block (128)
    constexpr int KROW = (DIN < 32) ? 32 : DIN;    // padded row length (k)
    constexpr int NKC  = KROW / 32;                // MFMA k-chunks of 32
    constexpr int NT   = DOUT / 16;                // n-tiles per wave
    constexpr int LDA  = KROW * 2 + 16;            // A LDS row stride (bytes)
    constexpr int LDW  = 80;                       // W LDS row stride (32 k * 2B + 16)
    constexpr int NP   = KROW / 16;                // k-pairs per row (32B units)
    __shared__ __align__(16) unsigned char lds[(size_t)BM * LDA + (size_t)2 * DOUT * LDW];
    unsigned char* Asm = lds;
    unsigned char* Wh  = lds + (size_t)BM * LDA;
    unsigned char* Wl  = Wh + (size_t)DOUT * LDW;

    const int row0 = blockIdx.x * BM;
    const int lane = threadIdx.x & 63;
    const int wave = __builtin_amdgcn_readfirstlane((int)(threadIdx.x >> 6));
    const int l15 = lane & 15, lhi = lane >> 4;

    f32x4 acc[NT];
#pragma unroll
    for (int t = 0; t < NT; ++t) acc[t] = (f32x4){0.f, 0.f, 0.f, 0.f};

    // ---- stage A (full DIN; one k-pair = 32B per item => one edge walk per thread) ----
    for (int i = threadIdx.x; i < BM * NP; i += THREADS) {
        int r = i / NP, jp = i % NP;
        f16x8 hv0 = {0, 0, 0, 0, 0, 0, 0, 0};
        f16x8 hv1 = {0, 0, 0, 0, 0, 0, 0, 0};
        int gr = row0 + r;
        const int k16 = jp * 16;
        if (gr < n && k16 < DIN) {
            if (MODE == M_PLAIN) {
                int ar = IN_PERM ? map[gr] : gr;
                const float* ap = Af + (size_t)ar * DIN + k16;
                float4 v0 = *(const float4*)(ap);
                float4 v1 = *(const float4*)(ap + 4);
                float4 v2 = *(const float4*)(ap + 8);
                float4 v3 = *(const float4*)(ap + 12);
                hv0[0] = (f16)v0.x; hv0[1] = (f16)v0.y; hv0[2] = (f16)v0.z; hv0[3] = (f16)v0.w;
                hv0[4] = (f16)v1.x; hv0[5] = (f16)v1.y; hv0[6] = (f16)v1.z; hv0[7] = (f16)v1.w;
                hv1[0] = (f16)v2.x; hv1[1] = (f16)v2.y; hv1[2] = (f16)v2.z; hv1[3] = (f16)v2.w;
                hv1[4] = (f16)v3.x; hv1[5] = (f16)v3.y; hv1[6] = (f16)v3.z; hv1[7] = (f16)v3.w;
            } else {
                const f16* ub = U + (size_t)gr * DIN + k16;
                f16x8 sa = *(const f16x8*)(ub);
                f16x8 sb = *(const f16x8*)(ub + 8);
                float sf[16], g[16];
#pragma unroll
                for (int q = 0; q < 8; ++q) {
                    sf[q] = (float)sa[q];
                    sf[q + 8] = (float)sb[q];
                }
#pragma unroll
                for (int q = 0; q < 16; ++q) {
                    if (MODE == M_SHARP_RELU) sf[q] = fmaxf(sf[q], 0.f);
                    g[q] = 0.f;
                }
                int e = offs[gr], e1 = offs[gr + 1];
                if (e < e1) {
                    const int last = e1 - 1;
                    for (; e < e1; e += 4) {
                        int i1 = (e + 1 < last) ? e + 1 : last;
                        int i2 = (e + 2 < last) ? e + 2 : last;
                        int i3 = (e + 3 < last) ? e + 3 : last;
                        int r0 = srcv[e], r1 = srcv[i1], r2 = srcv[i2], r3 = srcv[i3];
                        const f16* p0 = U + (size_t)r0 * DIN + k16;
                        const f16* p1 = U + (size_t)r1 * DIN + k16;
                        const f16* p2 = U + (size_t)r2 * DIN + k16;
                        const f16* p3 = U + (size_t)r3 * DIN + k16;
                        f16x8 t0a = *(const f16x8*)(p0), t0b = *(const f16x8*)(p0 + 8);
                        f16x8 t1a = *(const f16x8*)(p1), t1b = *(const f16x8*)(p1 + 8);
                        f16x8 t2a = *(const f16x8*)(p2), t2b = *(const f16x8*)(p2 + 8);
                        f16x8 t3a = *(const f16x8*)(p3), t3b = *(const f16x8*)(p3 + 8);
                        bool m1 = (e + 1 < e1), m2 = (e + 2 < e1), m3 = (e + 3 < e1);
#pragma unroll
                        for (int q = 0; q < 8; ++q) {
                            float a0 = (float)t0a[q], b0 = (float)t0b[q];
                            float a1 = (float)t1a[q], b1 = (float)t1b[q];
                            float a2 = (float)t2a[q], b2 = (float)t2b[q];
                            float a3 = (float)t3a[q], b3 = (float)t3b[q];
                            if (MODE == M_SHARP_RELU) {
                                a0 = fmaxf(a0, 0.f); a1 = fmaxf(a1, 0.f);
                                a2 = fmaxf(a2, 0.f); a3 = fmaxf(a3, 0.f);
                                b0 = fmaxf(b0, 0.f); b1 = fmaxf(b1, 0.f);
                                b2 = fmaxf(b2, 0.f); b3 = fmaxf(b3, 0.f);
                            }
                            a1 = m1 ? a1 : 0.f; b1 = m1 ? b1 : 0.f;
                            a2 = m2 ? a2 : 0.f; b2 = m2 ? b2 : 0.f;
                            a3 = m3 ? a3 : 0.f; b3 = m3 ? b3 : 0.f;
                            g[q] += (a0 + a1) + (a2 + a3);
                            g[q + 8] += (b0 + b1) + (b2 + b3);
                        }
                    }
                }
                float dv = gdinv[gr];
#pragma unroll
                for (int q = 0; q < 16; ++q) {
                    float v;
                    if (MODE == M_SMOOTH) {
                        v = fmaf(dv, g[q] + sf[q], gbias[k16 + q]);
                        v = fmaxf(v, 0.f);
                    } else {
                        v = dv * (2.f * sf[q] - g[q]);
                    }
                    if (q < 8) hv0[q] = (f16)v;
                    else       hv1[q - 8] = (f16)v;
                }
            }
        }
        unsigned char* dst = Asm + (size_t)r * LDA + jp * 32;
        *(f16x8*)(dst) = hv0;
        *(f16x8*)(dst + 16) = hv1;
    }

    // ---- k-chunk loop: stage W chunk in LDS, MFMA from LDS ----
    for (int kc = 0; kc < NKC; ++kc) {
        const int kofs = kc * 32;
        if (kc > 0) __syncthreads();             // protect W buffer reuse
        for (int i = threadIdx.x; i < DOUT * 4; i += THREADS) {
            int c = i / 4, j = i % 4;
            f16x8 h8 = {0, 0, 0, 0, 0, 0, 0, 0}, l8 = {0, 0, 0, 0, 0, 0, 0, 0};
            if (kofs + j * 8 < DIN) {
                h8 = *(const f16x8*)(Wth + (size_t)c * DIN + kofs + j * 8);
                l8 = *(const f16x8*)(Wtl + (size_t)c * DIN + kofs + j * 8);
            }
            *(f16x8*)(Wh + (size_t)c * LDW + j * 16) = h8;
            *(f16x8*)(Wl + (size_t)c * LDW + j * 16) = l8;
        }
        __syncthreads();

        f16x8 a = *(const f16x8*)(Asm + (size_t)(wave * 16 + l15) * LDA + kc * 64 + lhi * 16);
#pragma unroll
        for (int t = 0; t < NT; ++t) {
            f16x8 bh = *(const f16x8*)(Wh + (size_t)(t * 16 + l15) * LDW + lhi * 16);
            f16x8 bl = *(const f16x8*)(Wl + (size_t)(t * 16 + l15) * LDW + lhi * 16);
            acc[t] = __builtin_amdgcn_mfma_f32_16x16x32_f16(a, bh, acc[t], 0, 0, 0);
            acc[t] = __builtin_amdgcn_mfma_f32_16x16x32_f16(a, bl, acc[t], 0, 0, 0);
        }
    }

    // ---- epilogue: C/D layout col=l&15, row=(l>>4)*4+r ----
    const int rbase = row0 + wave * 16 + (lhi << 2);
    float rsv[4]; int om[4];
#pragma unroll
    for (int r = 0; r < 4; ++r) {
        int row = rbase + r;
        bool ok = row < n;
        rsv[r] = (SCALE_ROW && ok) ? rs[row] : 1.0f;
        om[r] = ok ? (OUT_PERM ? map[row] : row) : -1;
    }
#pragma unroll
    for (int t = 0; t < NT; ++t) {
        int colb = t * 16 + l15;
        float b = ADD_BIAS ? bias[colb] : 0.f;
#pragma unroll
        for (int r = 0; r < 4; ++r) {
            if (om[r] < 0) continue;
            float v = acc[t][r] + b;
            if (RELU_OUT) v = fmaxf(v, 0.f);
            if (SCALE_ROW) v *= rsv[r];
            if (OUT_F32) outf[(size_t)om[r] * DOUT + colb] = v;
            else         outh[(size_t)om[r] * DOUT + colb] = (f16)v;
        }
    }
}

// ---------------- standalone smooth gather d=16, f16 -> f16 (L3->L4 boundary) ----------------
// Z' = ps[c] * ( dinv[c]*(Σ u[src] + u[c]) + bias ) — one thread per node, full 32B row.

__global__ __launch_bounds__(256) void gather16(
        const f16* __restrict__ u, const int* __restrict__ offs,
        const int* __restrict__ src, const float* __restrict__ dinv,
        const float* __restrict__ ps, const float* __restrict__ bias,
        f16* __restrict__ out, int n) {
    int node = blockIdx.x * blockDim.x + threadIdx.x;
    if (node >= n) return;

    const f16* ub = u + (size_t)node * 16;
    f16x8 sa = *(const f16x8*)(ub);
    f16x8 sb = *(const f16x8*)(ub + 8);
    float g[16];
#pragma unroll
    for (int q = 0; q < 16; ++q) g[q] = 0.f;
    int e = offs[node], e1 = offs[node + 1];
    if (e < e1) {
        const int last = e1 - 1;
        for (; e < e1; e += 4) {
            int i1 = (e + 1 < last) ? e + 1 : last;
            int i2 = (e + 2 < last) ? e + 2 : last;
            int i3 = (e + 3 < last) ? e + 3 : last;
            int r0 = src[e], r1 = src[i1], r2 = src[i2], r3 = src[i3];
            const f16* p0 = u + (size_t)r0 * 16;
            const f16* p1 = u + (size_t)r1 * 16;
            const f16* p2 = u + (size_t)r2 * 16;
            const f16* p3 = u + (size_t)r3 * 16;
            f16x8 t0a = *(const f16x8*)(p0), t0b = *(const f16x8*)(p0 + 8);
            f16x8 t1a = *(const f16x8*)(p1), t1b = *(const f16x8*)(p1 + 8);
            f16x8 t2a = *(const f16x8*)(p2), t2b = *(const f16x8*)(p2 + 8);
            f16x8 t3a = *(const f16x8*)(p3), t3b = *(const f16x8*)(p3 + 8);
            bool m1 = (e + 1 < e1), m2 = (e + 2 < e1), m3 = (e + 3 < e1);
#pragma unroll
            for (int q = 0; q < 8; ++q) {
                float a0 = (float)t0a[q], b0 = (float)t0b[q];
                float a1 = m1 ? (float)t1a[q] : 0.f, b1 = m1 ? (float)t1b[q] : 0.f;
                float a2 = m2 ? (float)t2a[q] : 0.f, b2 = m2 ? (float)t2b[q] : 0.f;
                float a3 = m3 ? (float)t3a[q] : 0.f, b3 = m3 ? (float)t3b[q] : 0.f;
                g[q] += (a0 + a1) + (a2 + a3);
                g[q + 8] += (b0 + b1) + (b2 + b3);
            }
        }
    }
    float dv = dinv[node], p = ps[node];
    f16x8 oa, ob;
#pragma unroll
    for (int q = 0; q < 8; ++q) {
        oa[q] = (f16)(p * fmaf(dv, g[q] + (float)sa[q], bias[q]));
        ob[q] = (f16)(p * fmaf(dv, g[q + 8] + (float)sb[q], bias[q + 8]));
    }
    f16* ob_ptr = out + (size_t)node * 16;
    *(f16x8*)(ob_ptr) = oa;
    *(f16x8*)(ob_ptr + 8) = ob;
}

// ---------------- host orchestration ----------------

extern "C" void kernel_launch(void* const* d_in, const int* in_sizes, int n_in,
                              void* d_out, int out_size, void* d_ws, size_t ws_size,
                              hipStream_t stream) {
    const int T = 128;
    const int n = in_sizes[0] / T;        // 100000
    const int E = in_sizes[1] / 2;        // 600000

    const float* x   = (const float*)d_in[0];
    const int* eidx  = (const int*)d_in[1];
    const int* row   = eidx;
    const int* col   = eidx + E;
    const float* We1 = (const float*)d_in[2];
    const float* be1 = (const float*)d_in[3];
    const float* We2 = (const float*)d_in[4];
    const float* be2 = (const float*)d_in[5];
    const float* We3 = (const float*)d_in[6];
    const float* be3 = (const float*)d_in[7];
    const float* Wd1 = (const float*)d_in[8];
    const float* bd1 = (const float*)d_in[9];
    const float* Wd2 = (const float*)d_in[10];
    const float* bd2 = (const float*)d_in[11];
    const float* Wd3 = (const float*)d_in[12];
    const float* bd3 = (const float*)d_in[13];
    float* out = (float*)d_out;

    // workspace layout (all 16B aligned)
    char* base = (char*)d_ws;
    int*   deg      = (int*)base;   base += (size_t)n * 4;
    int*   offs     = (int*)base;   base += (size_t)(n + 4) * 4;
    int*   cursor   = (int*)base;   base += (size_t)(n + 4) * 4;
    int*   bhist    = (int*)base;   base += (size_t)512 * NBINS * 4;
    int*   bintot   = (int*)base;   base += (size_t)NBINS * 4;
    int*   binbase  = (int*)base;   base += (size_t)NBINS * 4;
    int*   edgebase = (int*)base;   base += (size_t)NBINS * 4;
    int*   order    = (int*)base;   base += (size_t)n * 4;
    int*   slotof   = (int*)base;   base += (size_t)n * 4;
    float* dinv_s   = (float*)base; base += (size_t)n * 4;
    float* dinv_h   = (float*)base; base += (size_t)n * 4;
    int*   src      = (int*)base;   base += (size_t)E * 4;
    f16*   wt_hi    = (f16*)base;   base += (size_t)21504 * 2 + 64;
    f16*   wt_lo    = (f16*)base;   base += (size_t)21504 * 2 + 64;
    f16*   bufA     = (f16*)base;   base += (size_t)n * 64 * 2;
    f16*   bufB     = (f16*)base;   base += (size_t)n * 64 * 2;
    (void)ws_size;

    const int BLK = 256;
    const int nhb = ceil_div(n, SCAN_BLK);

    // --- degrees ---
    zero_kernel<<<ceil_div(n, BLK), BLK, 0, stream>>>(deg, n);
    deg_kernel<<<ceil_div(E, BLK), BLK, 0, stream>>>(col, deg, E);

    // --- counting sort by degree + fused dinv/offs + CSR fill ---
    hist_kernel<<<nhb, SCAN_BLK, 0, stream>>>(deg, bhist, n);
    binscan_kernel<<<NBINS, 512, 0, stream>>>(bhist, bintot, nhb);
    base_scan_kernel<<<1, NBINS, 0, stream>>>(bintot, binbase, edgebase);
    place_kernel<<<nhb, SCAN_BLK, 0, stream>>>(
        deg, bhist, binbase, edgebase, order, slotof, dinv_s, dinv_h, offs, cursor, n, E);
    csr_fill_kernel<<<ceil_div(E, BLK), BLK, 0, stream>>>(row, col, slotof, cursor, src, E);

    // --- W transpose + f16 split (once per launch) ---
    WPtrs wp; wp.p[0] = We1; wp.p[1] = We2; wp.p[2] = We3;
    wp.p[3] = Wd1; wp.p[4] = Wd2; wp.p[5] = Wd3;
    wsplit_kernel<<<ceil_div(21504, BLK), BLK, 0, stream>>>(wp, wt_hi, wt_lo);

    const int ggrid = ceil_div(n, 128);

    // K1: u1 = dinv_s ⊙ (x[order] @ We1)                     [PLAIN]
    gemm_fused<128, 64, 8, M_PLAIN, false, false, true, true, false, false>
        <<<ggrid, 512, 0, stream>>>(
        x, nullptr, wt_hi + 0, wt_lo + 0, nullptr, nullptr, nullptr, nullptr,
        nullptr, dinv_s, order, nullptr, bufA, n);

    // K2: a1 = relu(dinv_s[c](Σu1+u1[c]) + be1); u2 = dinv_s ⊙ (a1 @ We2)   [SMOOTH]
    gemm_fused<64, 32, 8, M_SMOOTH, false, false, true, false, false, false>
        <<<ggrid, 512, 0, stream>>>(
        nullptr, bufA, wt_hi + 8192, wt_lo + 8192, be1, dinv_s, offs, src,
        nullptr, dinv_s, nullptr, nullptr, bufB, n);

    // K3: a2 = relu(dinv_s[c](Σu2+u2[c]) + be2); u3 = dinv_s ⊙ (a2 @ We3)   [SMOOTH]
    gemm_fused<32, 16, 8, M_SMOOTH, false, false, true, false, false, false>
        <<<ggrid, 512, 0, stream>>>(
        nullptr, bufB, wt_hi + 10240, wt_lo + 10240, be2, dinv_s, offs, src,
        nullptr, dinv_s, nullptr, nullptr, bufA, n);

    // K4: Z' = dinv_h ⊙ (dinv_s[c](Σu3+u3[c]) + be3)         [standalone gather]
    gather16<<<ceil_div(n, BLK), BLK, 0, stream>>>(
        bufA, offs, src, dinv_s, dinv_h, be3, bufB, n);

    // K5: P4 = dinv_h[c](2 relu(Z'[c]) - Σ relu(Z'[src])); u4 = dinv_h ⊙ relu(P4@Wd1+bd1)
    gemm_fused<16, 32, 8, M_SHARP_RELU, true, true, true, false, false, false>
        <<<ggrid, 512, 0, stream>>>(
        nullptr, bufB, wt_hi + 10752, wt_lo + 10752, nullptr, dinv_h, offs, src,
        bd1, dinv_h, nullptr, nullptr, bufA, n);

    // K6: P5 = dinv_h[c](2 u4[c] - Σ u4); u5 = dinv_h ⊙ relu(P5@Wd2+bd2)    [SHARP]
    gemm_fused<32, 64, 8, M_SHARP, true, true, true, false, false, false>
        <<<ggrid, 512, 0, stream>>>(
        nullptr, bufA, wt_hi + 11264, wt_lo + 11264, nullptr, dinv_h, offs, src,
        bd2, dinv_h, nullptr, nullptr, bufB, n);

    // K7: P6 = dinv_h[c](2 u5[c] - Σ u5); out[order] = P6 @ Wd3 + bd3       [SHARP]
    gemm_fused<64, 128, 8, M_SHARP, true, false, false, false, true, true>
        <<<ggrid, 512, 0, stream>>>(
        nullptr, bufB, wt_hi + 13312, wt_lo + 13312, nullptr, dinv_h, offs, src,
        bd3, nullptr, order, out, nullptr, n);
}

// Round 17
// 233.756 us; speedup vs baseline: 1.0334x; 1.0334x over previous
//
#include <hip/hip_runtime.h>

// GALA graph autoencoder on MI355X — round 17: r15 base (best, 219.5us) + batch-8
// clamped edge walk (one row-load round for deg<=8 instead of two) + fused place
// kernel (from r16; the k-pair retiling that regressed r16 is reverted).
// Pipeline: degree counting-sort relabel -> slot space; weightless algebra
// prop = dinv ⊙ (A^T (dinv ⊙ h)); propagation fused into consuming GEMM's A-staging
// (full-DIN, 16B slice per item); f16 intermediates; A_f16 x (W_hi+W_lo) f16 MFMA
// with LDS-staged W in KC=32 chunks; closed-form CSR offsets from degree histogram.

static inline int ceil_div(int a, int b) { return (a + b - 1) / b; }

#define SCAN_BLK 256
#define NBINS 128

typedef _Float16 f16;
typedef _Float16 f16x8 __attribute__((ext_vector_type(8)));
typedef float f32x4 __attribute__((ext_vector_type(4)));

// ---------------- zero fill ----------------

__global__ void zero_kernel(int* __restrict__ p, int n) {
    int i = blockIdx.x * blockDim.x + threadIdx.x;
    if (i < n) p[i] = 0;
}

// ---------------- degree ----------------

__global__ void deg_kernel(const int* __restrict__ col, int* __restrict__ deg, int E) {
    int e = blockIdx.x * blockDim.x + threadIdx.x;
    if (e < E) atomicAdd(&deg[col[e]], 1);
}

// ---------------- counting sort by degree (block-aggregated, deterministic) ----------------

__global__ void hist_kernel(const int* __restrict__ deg, int* __restrict__ blockhist, int n) {
    __shared__ int lh[NBINS];
    if (threadIdx.x < NBINS) lh[threadIdx.x] = 0;
    __syncthreads();
    int i = blockIdx.x * SCAN_BLK + threadIdx.x;
    if (i < n) {
        int d = deg[i]; if (d >= NBINS) d = NBINS - 1;
        atomicAdd(&lh[d], 1);
    }
    __syncthreads();
    if (threadIdx.x < NBINS) blockhist[blockIdx.x * NBINS + threadIdx.x] = lh[threadIdx.x];
}

__global__ void binscan_kernel(int* __restrict__ blockhist, int* __restrict__ bintot, int nb) {
    __shared__ int s[512];
    int bin = blockIdx.x, t = threadIdx.x;
    int v = (t < nb) ? blockhist[t * NBINS + bin] : 0;
    s[t] = v;
    __syncthreads();
    for (int st = 1; st < 512; st <<= 1) {
        int a = (t >= st) ? s[t - st] : 0;
        __syncthreads();
        s[t] += a;
        __syncthreads();
    }
    if (t < nb) blockhist[t * NBINS + bin] = s[t] - v;
    if (t == 0) bintot[bin] = s[511];
}

// 1 block, NBINS threads: binbase = exclscan(bintot); edgebase = exclscan(d*bintot[d])
__global__ void base_scan_kernel(const int* __restrict__ bintot, int* __restrict__ binbase,
                                 int* __restrict__ edgebase) {
    __shared__ int s[NBINS], se[NBINS];
    int t = threadIdx.x;
    int v = bintot[t];
    int ve = v * t;
    s[t] = v; se[t] = ve;
    __syncthreads();
    for (int st = 1; st < NBINS; st <<= 1) {
        int a = (t >= st) ? s[t - st] : 0;
        int ae = (t >= st) ? se[t - st] : 0;
        __syncthreads();
        s[t] += a; se[t] += ae;
        __syncthreads();
    }
    binbase[t] = s[t] - v;
    edgebase[t] = se[t] - ve;
}

// placement + permuted dinv + closed-form CSR offsets (fused)
__global__ void place_kernel(const int* __restrict__ deg, const int* __restrict__ blockhist,
                             const int* __restrict__ binbase, const int* __restrict__ edgebase,
                             int* __restrict__ order, int* __restrict__ slotof,
                             float* __restrict__ dinv_s, float* __restrict__ dinv_h,
                             int* __restrict__ offs, int* __restrict__ cursor, int n, int E) {
    __shared__ int lh[NBINS];
    if (threadIdx.x < NBINS) lh[threadIdx.x] = 0;
    __syncthreads();
    int i = blockIdx.x * SCAN_BLK + threadIdx.x;
    if (i < n) {
        int dd = deg[i];
        int b = dd < NBINS ? dd : NBINS - 1;
        int r = atomicAdd(&lh[b], 1);
        int slot = binbase[b] + blockhist[blockIdx.x * NBINS + b] + r;
        order[slot] = i;
        slotof[i] = slot;
        float d = (float)dd;
        dinv_s[slot] = rsqrtf(d + 1.0f);   // smooth: indeg + 1
        dinv_h[slot] = rsqrtf(d + 2.0f);   // sharp:  indeg + 2
        int o = edgebase[dd] + dd * (slot - binbase[dd]);
        offs[slot] = o;
        cursor[slot] = o;
        if (i == 0) offs[n] = E;
    }
}

__global__ void csr_fill_kernel(const int* __restrict__ row, const int* __restrict__ col,
                                const int* __restrict__ slotof, int* __restrict__ cursor,
                                int* __restrict__ src, int E) {
    int e = blockIdx.x * blockDim.x + threadIdx.x;
    if (e >= E) return;
    int cs = slotof[col[e]];
    int p = atomicAdd(&cursor[cs], 1);
    src[p] = slotof[row[e]];
}

// ---------------- W pre-transpose + split (f32 [DIN][DOUT] -> f16 hi/lo [DOUT][DIN]) ----------------

struct WPtrs { const float* p[6]; };

__global__ void wsplit_kernel(WPtrs wp, f16* __restrict__ wt_hi, f16* __restrict__ wt_lo) {
    const int din[6]  = {128, 64, 32, 16, 32, 64};
    const int dout[6] = {64, 32, 16, 32, 64, 128};
    const int off[6]  = {0, 8192, 10240, 10752, 11264, 13312};
    int t = blockIdx.x * blockDim.x + threadIdx.x;
    if (t >= 21504) return;
    int l = 0;
    while (l < 5 && t >= off[l + 1]) ++l;
    int idx = t - off[l];
    int c = idx / din[l], k = idx - c * din[l];
    float a = wp.p[l][k * dout[l] + c];
    f16 hi = (f16)a;
    f16 lo = (f16)(a - (float)hi);
    wt_hi[t] = hi;
    wt_lo[t] = lo;
}

// ---------------- fused gather + f16 MFMA GEMM ----------------
// A staged full-DIN in one pass (16B slice per item; batch-8 clamped edge walk —
// one round of 8 independent row loads covers deg<=8); W staged in LDS per KC=32
// chunk. Staging modes:
//   PLAIN:      v = Af32[perm(row)]
//   SMOOTH:     v = relu( gdinv[r]*(Σ u[src] + u[r]) + gbias )
//   SHARP:      v = gdinv[r]*(2*u[r] - Σ u[src])
//   SHARP_RELU: same as SHARP, relu applied to gathered values
// C = A_f16 @ (W_hi + W_lo), 2 MFMA passes. Epilogue: bias/relu/scale; f16 or f32 out.

#define M_PLAIN 0
#define M_SMOOTH 1
#define M_SHARP 2
#define M_SHARP_RELU 3

template <int DIN, int DOUT, int WAVES, int MODE, bool ADD_BIAS, bool RELU_OUT,
          bool SCALE_ROW, bool IN_PERM, bool OUT_PERM, bool OUT_F32>
__global__ __launch_bounds__(WAVES * 64) void gemm_fused(
        const float* __restrict__ Af, const f16* __restrict__ U,
        const f16* __restrict__ Wth, const f16* __restrict__ Wtl,
        const float* __restrict__ gbias, const float* __restrict__ gdinv,
        const int* __restrict__ offs, const int* __restrict__ srcv,
        const float* __restrict__ bias, const float* __restrict__ rs,
        const int* __restrict__ map, float* __restrict__ outf,
        f16* __restrict__ outh, int n) {
    constexpr int THREADS = WAVES * 64;
    constexpr int BM   = WAVES * 16;               // rows per block (128)
    constexpr int KROW = (DIN < 32) ? 32 : DIN;    // padded row length (k)
    constexpr int NKC  = KROW / 32;                // MFMA k-chunks of 32
    constexpr int NT   = DOUT / 16;                // n-tiles per wave
    constexpr int LDA  = KROW * 2 + 16;            // A LDS row stride (bytes)
    constexpr int LDW  = 80;                       // W LDS row stride (32 k * 2B + 16)
    constexpr int AGF  = KROW / 8;                 // f16x8 groups per A row
    __shared__ __align__(16) unsigned char lds[(size_t)BM * LDA + (size_t)2 * DOUT * LDW];
    unsigned char* Asm = lds;
    unsigned char* Wh  = lds + (size_t)BM * LDA;
    unsigned char* Wl  = Wh + (size_t)DOUT * LDW;

    const int row0 = blockIdx.x * BM;
    const int lane = threadIdx.x & 63;
    const int wave = __builtin_amdgcn_readfirstlane((int)(threadIdx.x >> 6));
    const int l15 = lane & 15, lhi = lane >> 4;

    f32x4 acc[NT];
#pragma unroll
    for (int t = 0; t < NT; ++t) acc[t] = (f32x4){0.f, 0.f, 0.f, 0.f};

    // ---- stage A (full DIN; batch-8 clamped edge walk) ----
    for (int i = threadIdx.x; i < BM * AGF; i += THREADS) {
        int r = i / AGF, j = i % AGF;
        f16x8 hv = {0, 0, 0, 0, 0, 0, 0, 0};
        int gr = row0 + r;
        const int k8 = j * 8;
        if (gr < n && k8 < DIN) {
            if (MODE == M_PLAIN) {
                int ar = IN_PERM ? map[gr] : gr;
                float4 v0 = *(const float4*)(Af + (size_t)ar * DIN + k8);
                float4 v1 = *(const float4*)(Af + (size_t)ar * DIN + k8 + 4);
                hv[0] = (f16)v0.x; hv[1] = (f16)v0.y; hv[2] = (f16)v0.z; hv[3] = (f16)v0.w;
                hv[4] = (f16)v1.x; hv[5] = (f16)v1.y; hv[6] = (f16)v1.z; hv[7] = (f16)v1.w;
            } else {
                f16x8 s8 = *(const f16x8*)(U + (size_t)gr * DIN + k8);
                float sf[8], g[8];
#pragma unroll
                for (int q = 0; q < 8; ++q) {
                    sf[q] = (float)s8[q];
                    if (MODE == M_SHARP_RELU) sf[q] = fmaxf(sf[q], 0.f);
                    g[q] = 0.f;
                }
                int e = offs[gr], e1 = offs[gr + 1];
                if (e < e1) {
                    const int last = e1 - 1;
                    for (; e < e1; e += 8) {
                        // clamped indices: tail re-loads last edge's row (L1-hit),
                        // accumulation predicated. One round of 8 independent loads.
                        int i1 = (e + 1 < last) ? e + 1 : last;
                        int i2 = (e + 2 < last) ? e + 2 : last;
                        int i3 = (e + 3 < last) ? e + 3 : last;
                        int i4 = (e + 4 < last) ? e + 4 : last;
                        int i5 = (e + 5 < last) ? e + 5 : last;
                        int i6 = (e + 6 < last) ? e + 6 : last;
                        int i7 = (e + 7 < last) ? e + 7 : last;
                        int r0 = srcv[e],  r1 = srcv[i1], r2 = srcv[i2], r3 = srcv[i3];
                        int r4 = srcv[i4], r5 = srcv[i5], r6 = srcv[i6], r7 = srcv[i7];
                        f16x8 t0 = *(const f16x8*)(U + (size_t)r0 * DIN + k8);
                        f16x8 t1 = *(const f16x8*)(U + (size_t)r1 * DIN + k8);
                        f16x8 t2 = *(const f16x8*)(U + (size_t)r2 * DIN + k8);
                        f16x8 t3 = *(const f16x8*)(U + (size_t)r3 * DIN + k8);
                        f16x8 t4 = *(const f16x8*)(U + (size_t)r4 * DIN + k8);
                        f16x8 t5 = *(const f16x8*)(U + (size_t)r5 * DIN + k8);
                        f16x8 t6 = *(const f16x8*)(U + (size_t)r6 * DIN + k8);
                        f16x8 t7 = *(const f16x8*)(U + (size_t)r7 * DIN + k8);
                        bool m1 = (e + 1 < e1), m2 = (e + 2 < e1), m3 = (e + 3 < e1);
                        bool m4 = (e + 4 < e1), m5 = (e + 5 < e1), m6 = (e + 6 < e1);
                        bool m7 = (e + 7 < e1);
#pragma unroll
                        for (int q = 0; q < 8; ++q) {
                            float a0 = (float)t0[q];
                            float a1 = (float)t1[q], a2 = (float)t2[q], a3 = (float)t3[q];
                            float a4 = (float)t4[q], a5 = (float)t5[q], a6 = (float)t6[q];
                            float a7 = (float)t7[q];
                            if (MODE == M_SHARP_RELU) {
                                a0 = fmaxf(a0, 0.f); a1 = fmaxf(a1, 0.f);
                                a2 = fmaxf(a2, 0.f); a3 = fmaxf(a3, 0.f);
                                a4 = fmaxf(a4, 0.f); a5 = fmaxf(a5, 0.f);
                                a6 = fmaxf(a6, 0.f); a7 = fmaxf(a7, 0.f);
                            }
                            a1 = m1 ? a1 : 0.f; a2 = m2 ? a2 : 0.f; a3 = m3 ? a3 : 0.f;
                            a4 = m4 ? a4 : 0.f; a5 = m5 ? a5 : 0.f; a6 = m6 ? a6 : 0.f;
                            a7 = m7 ? a7 : 0.f;
                            g[q] += ((a0 + a1) + (a2 + a3)) + ((a4 + a5) + (a6 + a7));
                        }
                    }
                }
                float dv = gdinv[gr];
#pragma unroll
                for (int q = 0; q < 8; ++q) {
                    float v;
                    if (MODE == M_SMOOTH) {
                        v = fmaf(dv, g[q] + sf[q], gbias[k8 + q]);
                        v = fmaxf(v, 0.f);
                    } else {
                        v = dv * (2.f * sf[q] - g[q]);
                    }
                    hv[q] = (f16)v;
                }
            }
        }
        *(f16x8*)(Asm + (size_t)r * LDA + j * 16) = hv;
    }

    // ---- k-chunk loop: stage W chunk in LDS, MFMA from LDS ----
    for (int kc = 0; kc < NKC; ++kc) {
        const int kofs = kc * 32;
        if (kc > 0) __syncthreads();             // protect W buffer reuse
        for (int i = threadIdx.x; i < DOUT * 4; i += THREADS) {
            int c = i / 4, j = i % 4;
            f16x8 h8 = {0, 0, 0, 0, 0, 0, 0, 0}, l8 = {0, 0, 0, 0, 0, 0, 0, 0};
            if (kofs + j * 8 < DIN) {
                h8 = *(const f16x8*)(Wth + (size_t)c * DIN + kofs + j * 8);
                l8 = *(const f16x8*)(Wtl + (size_t)c * DIN + kofs + j * 8);
            }
            *(f16x8*)(Wh + (size_t)c * LDW + j * 16) = h8;
            *(f16x8*)(Wl + (size_t)c * LDW + j * 16) = l8;
        }
        __syncthreads();

        f16x8 a = *(const f16x8*)(Asm + (size_t)(wave * 16 + l15) * LDA + kc * 64 + lhi * 16);
#pragma unroll
        for (int t = 0; t < NT; ++t) {
            f16x8 bh = *(const f16x8*)(Wh + (size_t)(t * 16 + l15) * LDW + lhi * 16);
            f16x8 bl = *(const f16x8*)(Wl + (size_t)(t * 16 + l15) * LDW + lhi * 16);
            acc[t] = __builtin_amdgcn_mfma_f32_16x16x32_f16(a, bh, acc[t], 0, 0, 0);
            acc[t] = __builtin_amdgcn_mfma_f32_16x16x32_f16(a, bl, acc[t], 0, 0, 0);
        }
    }

    // ---- epilogue: C/D layout col=l&15, row=(l>>4)*4+r ----
    const int rbase = row0 + wave * 16 + (lhi << 2);
    float rsv[4]; int om[4];
#pragma unroll
    for (int r = 0; r < 4; ++r) {
        int row = rbase + r;
        bool ok = row < n;
        rsv[r] = (SCALE_ROW && ok) ? rs[row] : 1.0f;
        om[r] = ok ? (OUT_PERM ? map[row] : row) : -1;
    }
#pragma unroll
    for (int t = 0; t < NT; ++t) {
        int colb = t * 16 + l15;
        float b = ADD_BIAS ? bias[colb] : 0.f;
#pragma unroll
        for (int r = 0; r < 4; ++r) {
            if (om[r] < 0) continue;
            float v = acc[t][r] + b;
            if (RELU_OUT) v = fmaxf(v, 0.f);
            if (SCALE_ROW) v *= rsv[r];
            if (OUT_F32) outf[(size_t)om[r] * DOUT + colb] = v;
            else         outh[(size_t)om[r] * DOUT + colb] = (f16)v;
        }
    }
}

// ---------------- standalone smooth gather d=16, f16 -> f16 (L3->L4 boundary) ----------------
// Z' = ps[c] * ( dinv[c]*(Σ u[src] + u[c]) + bias ) — batch-8 clamped walk, 2 thr/node.

__global__ __launch_bounds__(256) void gather16(
        const f16* __restrict__ u, const int* __restrict__ offs,
        const int* __restrict__ src, const float* __restrict__ dinv,
        const float* __restrict__ ps, const float* __restrict__ bias,
        f16* __restrict__ out, int n) {
    int idx = blockIdx.x * blockDim.x + threadIdx.x;
    int node = idx >> 1;
    if (node >= n) return;
    int d8 = (idx & 1) * 8;

    f16x8 s8 = *(const f16x8*)(u + (size_t)node * 16 + d8);
    float g[8];
#pragma unroll
    for (int q = 0; q < 8; ++q) g[q] = 0.f;
    int e = offs[node], e1 = offs[node + 1];
    if (e < e1) {
        const int last = e1 - 1;
        for (; e < e1; e += 8) {
            int i1 = (e + 1 < last) ? e + 1 : last;
            int i2 = (e + 2 < last) ? e + 2 : last;
            int i3 = (e + 3 < last) ? e + 3 : last;
            int i4 = (e + 4 < last) ? e + 4 : last;
            int i5 = (e + 5 < last) ? e + 5 : last;
            int i6 = (e + 6 < last) ? e + 6 : last;
            int i7 = (e + 7 < last) ? e + 7 : last;
            int r0 = src[e],  r1 = src[i1], r2 = src[i2], r3 = src[i3];
            int r4 = src[i4], r5 = src[i5], r6 = src[i6], r7 = src[i7];
            f16x8 t0 = *(const f16x8*)(u + (size_t)r0 * 16 + d8);
            f16x8 t1 = *(const f16x8*)(u + (size_t)r1 * 16 + d8);
            f16x8 t2 = *(const f16x8*)(u + (size_t)r2 * 16 + d8);
            f16x8 t3 = *(const f16x8*)(u + (size_t)r3 * 16 + d8);
            f16x8 t4 = *(const f16x8*)(u + (size_t)r4 * 16 + d8);
            f16x8 t5 = *(const f16x8*)(u + (size_t)r5 * 16 + d8);
            f16x8 t6 = *(const f16x8*)(u + (size_t)r6 * 16 + d8);
            f16x8 t7 = *(const f16x8*)(u + (size_t)r7 * 16 + d8);
            bool m1 = (e + 1 < e1), m2 = (e + 2 < e1), m3 = (e + 3 < e1);
            bool m4 = (e + 4 < e1), m5 = (e + 5 < e1), m6 = (e + 6 < e1);
            bool m7 = (e + 7 < e1);
#pragma unroll
            for (int q = 0; q < 8; ++q) {
                float a0 = (float)t0[q];
                float a1 = m1 ? (float)t1[q] : 0.f;
                float a2 = m2 ? (float)t2[q] : 0.f;
                float a3 = m3 ? (float)t3[q] : 0.f;
                float a4 = m4 ? (float)t4[q] : 0.f;
                float a5 = m5 ? (float)t5[q] : 0.f;
                float a6 = m6 ? (float)t6[q] : 0.f;
                float a7 = m7 ? (float)t7[q] : 0.f;
                g[q] += ((a0 + a1) + (a2 + a3)) + ((a4 + a5) + (a6 + a7));
            }
        }
    }
    float dv = dinv[node], p = ps[node];
    f16x8 o;
#pragma unroll
    for (int q = 0; q < 8; ++q) {
        float v = p * (fmaf(dv, g[q] + (float)s8[q], bias[d8 + q]));
        o[q] = (f16)v;
    }
    *(f16x8*)(out + (size_t)node * 16 + d8) = o;
}

// ---------------- host orchestration ----------------

extern "C" void kernel_launch(void* const* d_in, const int* in_sizes, int n_in,
                              void* d_out, int out_size, void* d_ws, size_t ws_size,
                              hipStream_t stream) {
    const int T = 128;
    const int n = in_sizes[0] / T;        // 100000
    const int E = in_sizes[1] / 2;        // 600000

    const float* x   = (const float*)d_in[0];
    const int* eidx  = (const int*)d_in[1];
    const int* row   = eidx;
    const int* col   = eidx + E;
    const float* We1 = (const float*)d_in[2];
    const float* be1 = (const float*)d_in[3];
    const float* We2 = (const float*)d_in[4];
    const float* be2 = (const float*)d_in[5];
    const float* We3 = (const float*)d_in[6];
    const float* be3 = (const float*)d_in[7];
    const float* Wd1 = (const float*)d_in[8];
    const float* bd1 = (const float*)d_in[9];
    const float* Wd2 = (const float*)d_in[10];
    const float* bd2 = (const float*)d_in[11];
    const float* Wd3 = (const float*)d_in[12];
    const float* bd3 = (const float*)d_in[13];
    float* out = (float*)d_out;

    // workspace layout (all 16B aligned)
    char* base = (char*)d_ws;
    int*   deg      = (int*)base;   base += (size_t)n * 4;
    int*   offs     = (int*)base;   base += (size_t)(n + 4) * 4;
    int*   cursor   = (int*)base;   base += (size_t)(n + 4) * 4;
    int*   bhist    = (int*)base;   base += (size_t)512 * NBINS * 4;
    int*   bintot   = (int*)base;   base += (size_t)NBINS * 4;
    int*   binbase  = (int*)base;   base += (size_t)NBINS * 4;
    int*   edgebase = (int*)base;   base += (size_t)NBINS * 4;
    int*   order    = (int*)base;   base += (size_t)n * 4;
    int*   slotof   = (int*)base;   base += (size_t)n * 4;
    float* dinv_s   = (float*)base; base += (size_t)n * 4;
    float* dinv_h   = (float*)base; base += (size_t)n * 4;
    int*   src      = (int*)base;   base += (size_t)E * 4;
    f16*   wt_hi    = (f16*)base;   base += (size_t)21504 * 2 + 64;
    f16*   wt_lo    = (f16*)base;   base += (size_t)21504 * 2 + 64;
    f16*   bufA     = (f16*)base;   base += (size_t)n * 64 * 2;
    f16*   bufB     = (f16*)base;   base += (size_t)n * 64 * 2;
    (void)ws_size;

    const int BLK = 256;
    const int nhb = ceil_div(n, SCAN_BLK);

    // --- degrees ---
    zero_kernel<<<ceil_div(n, BLK), BLK, 0, stream>>>(deg, n);
    deg_kernel<<<ceil_div(E, BLK), BLK, 0, stream>>>(col, deg, E);

    // --- counting sort by degree + fused dinv/offs + CSR fill ---
    hist_kernel<<<nhb, SCAN_BLK, 0, stream>>>(deg, bhist, n);
    binscan_kernel<<<NBINS, 512, 0, stream>>>(bhist, bintot, nhb);
    base_scan_kernel<<<1, NBINS, 0, stream>>>(bintot, binbase, edgebase);
    place_kernel<<<nhb, SCAN_BLK, 0, stream>>>(
        deg, bhist, binbase, edgebase, order, slotof, dinv_s, dinv_h, offs, cursor, n, E);
    csr_fill_kernel<<<ceil_div(E, BLK), BLK, 0, stream>>>(row, col, slotof, cursor, src, E);

    // --- W transpose + f16 split (once per launch) ---
    WPtrs wp; wp.p[0] = We1; wp.p[1] = We2; wp.p[2] = We3;
    wp.p[3] = Wd1; wp.p[4] = Wd2; wp.p[5] = Wd3;
    wsplit_kernel<<<ceil_div(21504, BLK), BLK, 0, stream>>>(wp, wt_hi, wt_lo);

    const int ggrid = ceil_div(n, 128);

    // K1: u1 = dinv_s ⊙ (x[order] @ We1)                     [PLAIN]
    gemm_fused<128, 64, 8, M_PLAIN, false, false, true, true, false, false>
        <<<ggrid, 512, 0, stream>>>(
        x, nullptr, wt_hi + 0, wt_lo + 0, nullptr, nullptr, nullptr, nullptr,
        nullptr, dinv_s, order, nullptr, bufA, n);

    // K2: a1 = relu(dinv_s[c](Σu1+u1[c]) + be1); u2 = dinv_s ⊙ (a1 @ We2)   [SMOOTH]
    gemm_fused<64, 32, 8, M_SMOOTH, false, false, true, false, false, false>
        <<<ggrid, 512, 0, stream>>>(
        nullptr, bufA, wt_hi + 8192, wt_lo + 8192, be1, dinv_s, offs, src,
        nullptr, dinv_s, nullptr, nullptr, bufB, n);

    // K3: a2 = relu(dinv_s[c](Σu2+u2[c]) + be2); u3 = dinv_s ⊙ (a2 @ We3)   [SMOOTH]
    gemm_fused<32, 16, 8, M_SMOOTH, false, false, true, false, false, false>
        <<<ggrid, 512, 0, stream>>>(
        nullptr, bufB, wt_hi + 10240, wt_lo + 10240, be2, dinv_s, offs, src,
        nullptr, dinv_s, nullptr, nullptr, bufA, n);

    // K4: Z' = dinv_h ⊙ (dinv_s[c](Σu3+u3[c]) + be3)         [standalone gather]
    gather16<<<ceil_div(n * 2, BLK), BLK, 0, stream>>>(
        bufA, offs, src, dinv_s, dinv_h, be3, bufB, n);

    // K5: P4 = dinv_h[c](2 relu(Z'[c]) - Σ relu(Z'[src])); u4 = dinv_h ⊙ relu(P4@Wd1+bd1)
    gemm_fused<16, 32, 8, M_SHARP_RELU, true, true, true, false, false, false>
        <<<ggrid, 512, 0, stream>>>(
        nullptr, bufB, wt_hi + 10752, wt_lo + 10752, nullptr, dinv_h, offs, src,
        bd1, dinv_h, nullptr, nullptr, bufA, n);

    // K6: P5 = dinv_h[c](2 u4[c] - Σ u4); u5 = dinv_h ⊙ relu(P5@Wd2+bd2)    [SHARP]
    gemm_fused<32, 64, 8, M_SHARP, true, true, true, false, false, false>
        <<<ggrid, 512, 0, stream>>>(
        nullptr, bufA, wt_hi + 11264, wt_lo + 11264, nullptr, dinv_h, offs, src,
        bd2, dinv_h, nullptr, nullptr, bufB, n);

    // K7: P6 = dinv_h[c](2 u5[c] - Σ u5); out[order] = P6 @ Wd3 + bd3       [SHARP]
    gemm_fused<64, 128, 8, M_SHARP, true, false, false, false, true, true>
        <<<ggrid, 512, 0, stream>>>(
        nullptr, bufB, wt_hi + 13312, wt_lo + 13312, nullptr, dinv_h, offs, src,
        bd3, nullptr, order, out, nullptr, n);
}

// Round 18
// 217.025 us; speedup vs baseline: 1.1131x; 1.0771x over previous
//
#include <hip/hip_runtime.h>

// GALA graph autoencoder on MI355X — round 18: revert to r15 (best, 219.5us) walk
// (batch-4 clamped predicated edge walk), keeping only the fused place_kernel from
// r16/r17 (dinv/offs at placement; one fewer launch). r16's k-pair retiling and
// r17's batch-8 walk both regressed and are dropped.
// Pipeline: degree counting-sort relabel -> slot space; weightless algebra
// prop = dinv ⊙ (A^T (dinv ⊙ h)); propagation fused into consuming GEMM's A-staging
// (full-DIN single edge walk); f16 intermediates; A_f16 x (W_hi+W_lo) f16 MFMA with
// LDS-staged W in KC=32 chunks; closed-form CSR offsets from degree histogram.

static inline int ceil_div(int a, int b) { return (a + b - 1) / b; }

#define SCAN_BLK 256
#define NBINS 128

typedef _Float16 f16;
typedef _Float16 f16x8 __attribute__((ext_vector_type(8)));
typedef float f32x4 __attribute__((ext_vector_type(4)));

// ---------------- zero fill ----------------

__global__ void zero_kernel(int* __restrict__ p, int n) {
    int i = blockIdx.x * blockDim.x + threadIdx.x;
    if (i < n) p[i] = 0;
}

// ---------------- degree ----------------

__global__ void deg_kernel(const int* __restrict__ col, int* __restrict__ deg, int E) {
    int e = blockIdx.x * blockDim.x + threadIdx.x;
    if (e < E) atomicAdd(&deg[col[e]], 1);
}

// ---------------- counting sort by degree (block-aggregated, deterministic) ----------------

__global__ void hist_kernel(const int* __restrict__ deg, int* __restrict__ blockhist, int n) {
    __shared__ int lh[NBINS];
    if (threadIdx.x < NBINS) lh[threadIdx.x] = 0;
    __syncthreads();
    int i = blockIdx.x * SCAN_BLK + threadIdx.x;
    if (i < n) {
        int d = deg[i]; if (d >= NBINS) d = NBINS - 1;
        atomicAdd(&lh[d], 1);
    }
    __syncthreads();
    if (threadIdx.x < NBINS) blockhist[blockIdx.x * NBINS + threadIdx.x] = lh[threadIdx.x];
}

__global__ void binscan_kernel(int* __restrict__ blockhist, int* __restrict__ bintot, int nb) {
    __shared__ int s[512];
    int bin = blockIdx.x, t = threadIdx.x;
    int v = (t < nb) ? blockhist[t * NBINS + bin] : 0;
    s[t] = v;
    __syncthreads();
    for (int st = 1; st < 512; st <<= 1) {
        int a = (t >= st) ? s[t - st] : 0;
        __syncthreads();
        s[t] += a;
        __syncthreads();
    }
    if (t < nb) blockhist[t * NBINS + bin] = s[t] - v;
    if (t == 0) bintot[bin] = s[511];
}

// 1 block, NBINS threads: binbase = exclscan(bintot); edgebase = exclscan(d*bintot[d])
__global__ void base_scan_kernel(const int* __restrict__ bintot, int* __restrict__ binbase,
                                 int* __restrict__ edgebase) {
    __shared__ int s[NBINS], se[NBINS];
    int t = threadIdx.x;
    int v = bintot[t];
    int ve = v * t;
    s[t] = v; se[t] = ve;
    __syncthreads();
    for (int st = 1; st < NBINS; st <<= 1) {
        int a = (t >= st) ? s[t - st] : 0;
        int ae = (t >= st) ? se[t - st] : 0;
        __syncthreads();
        s[t] += a; se[t] += ae;
        __syncthreads();
    }
    binbase[t] = s[t] - v;
    edgebase[t] = se[t] - ve;
}

// placement + permuted dinv + closed-form CSR offsets (fused)
__global__ void place_kernel(const int* __restrict__ deg, const int* __restrict__ blockhist,
                             const int* __restrict__ binbase, const int* __restrict__ edgebase,
                             int* __restrict__ order, int* __restrict__ slotof,
                             float* __restrict__ dinv_s, float* __restrict__ dinv_h,
                             int* __restrict__ offs, int* __restrict__ cursor, int n, int E) {
    __shared__ int lh[NBINS];
    if (threadIdx.x < NBINS) lh[threadIdx.x] = 0;
    __syncthreads();
    int i = blockIdx.x * SCAN_BLK + threadIdx.x;
    if (i < n) {
        int dd = deg[i];
        int b = dd < NBINS ? dd : NBINS - 1;
        int r = atomicAdd(&lh[b], 1);
        int slot = binbase[b] + blockhist[blockIdx.x * NBINS + b] + r;
        order[slot] = i;
        slotof[i] = slot;
        float d = (float)dd;
        dinv_s[slot] = rsqrtf(d + 1.0f);   // smooth: indeg + 1
        dinv_h[slot] = rsqrtf(d + 2.0f);   // sharp:  indeg + 2
        int o = edgebase[dd] + dd * (slot - binbase[dd]);
        offs[slot] = o;
        cursor[slot] = o;
        if (i == 0) offs[n] = E;
    }
}

__global__ void csr_fill_kernel(const int* __restrict__ row, const int* __restrict__ col,
                                const int* __restrict__ slotof, int* __restrict__ cursor,
                                int* __restrict__ src, int E) {
    int e = blockIdx.x * blockDim.x + threadIdx.x;
    if (e >= E) return;
    int cs = slotof[col[e]];
    int p = atomicAdd(&cursor[cs], 1);
    src[p] = slotof[row[e]];
}

// ---------------- W pre-transpose + split (f32 [DIN][DOUT] -> f16 hi/lo [DOUT][DIN]) ----------------

struct WPtrs { const float* p[6]; };

__global__ void wsplit_kernel(WPtrs wp, f16* __restrict__ wt_hi, f16* __restrict__ wt_lo) {
    const int din[6]  = {128, 64, 32, 16, 32, 64};
    const int dout[6] = {64, 32, 16, 32, 64, 128};
    const int off[6]  = {0, 8192, 10240, 10752, 11264, 13312};
    int t = blockIdx.x * blockDim.x + threadIdx.x;
    if (t >= 21504) return;
    int l = 0;
    while (l < 5 && t >= off[l + 1]) ++l;
    int idx = t - off[l];
    int c = idx / din[l], k = idx - c * din[l];
    float a = wp.p[l][k * dout[l] + c];
    f16 hi = (f16)a;
    f16 lo = (f16)(a - (float)hi);
    wt_hi[t] = hi;
    wt_lo[t] = lo;
}

// ---------------- fused gather + f16 MFMA GEMM ----------------
// A staged full-DIN in one pass (16B slice per item; batch-4 clamped predicated edge
// walk — r15's best-performing variant); W staged in LDS per KC=32 chunk. Modes:
//   PLAIN:      v = Af32[perm(row)]
//   SMOOTH:     v = relu( gdinv[r]*(Σ u[src] + u[r]) + gbias )
//   SHARP:      v = gdinv[r]*(2*u[r] - Σ u[src])
//   SHARP_RELU: same as SHARP, relu applied to gathered values
// C = A_f16 @ (W_hi + W_lo), 2 MFMA passes. Epilogue: bias/relu/scale; f16 or f32 out.

#define M_PLAIN 0
#define M_SMOOTH 1
#define M_SHARP 2
#define M_SHARP_RELU 3

template <int DIN, int DOUT, int WAVES, int MODE, bool ADD_BIAS, bool RELU_OUT,
          bool SCALE_ROW, bool IN_PERM, bool OUT_PERM, bool OUT_F32>
__global__ __launch_bounds__(WAVES * 64) void gemm_fused(
        const float* __restrict__ Af, const f16* __restrict__ U,
        const f16* __restrict__ Wth, const f16* __restrict__ Wtl,
        const float* __restrict__ gbias, const float* __restrict__ gdinv,
        const int* __restrict__ offs, const int* __restrict__ srcv,
        const float* __restrict__ bias, const float* __restrict__ rs,
        const int* __restrict__ map, float* __restrict__ outf,
        f16* __restrict__ outh, int n) {
    constexpr int THREADS = WAVES * 64;
    constexpr int BM   = WAVES * 16;               // rows per block (128)
    constexpr int KROW = (DIN < 32) ? 32 : DIN;    // padded row length (k)
    constexpr int NKC  = KROW / 32;                // MFMA k-chunks of 32
    constexpr int NT   = DOUT / 16;                // n-tiles per wave
    constexpr int LDA  = KROW * 2 + 16;            // A LDS row stride (bytes)
    constexpr int LDW  = 80;                       // W LDS row stride (32 k * 2B + 16)
    constexpr int AGF  = KROW / 8;                 // f16x8 groups per A row
    __shared__ __align__(16) unsigned char lds[(size_t)BM * LDA + (size_t)2 * DOUT * LDW];
    unsigned char* Asm = lds;
    unsigned char* Wh  = lds + (size_t)BM * LDA;
    unsigned char* Wl  = Wh + (size_t)DOUT * LDW;

    const int row0 = blockIdx.x * BM;
    const int lane = threadIdx.x & 63;
    const int wave = __builtin_amdgcn_readfirstlane((int)(threadIdx.x >> 6));
    const int l15 = lane & 15, lhi = lane >> 4;

    f32x4 acc[NT];
#pragma unroll
    for (int t = 0; t < NT; ++t) acc[t] = (f32x4){0.f, 0.f, 0.f, 0.f};

    // ---- stage A (full DIN, one pass; batch-4 clamped predicated edge walk) ----
    for (int i = threadIdx.x; i < BM * AGF; i += THREADS) {
        int r = i / AGF, j = i % AGF;
        f16x8 hv = {0, 0, 0, 0, 0, 0, 0, 0};
        int gr = row0 + r;
        const int k8 = j * 8;
        if (gr < n && k8 < DIN) {
            if (MODE == M_PLAIN) {
                int ar = IN_PERM ? map[gr] : gr;
                float4 v0 = *(const float4*)(Af + (size_t)ar * DIN + k8);
                float4 v1 = *(const float4*)(Af + (size_t)ar * DIN + k8 + 4);
                hv[0] = (f16)v0.x; hv[1] = (f16)v0.y; hv[2] = (f16)v0.z; hv[3] = (f16)v0.w;
                hv[4] = (f16)v1.x; hv[5] = (f16)v1.y; hv[6] = (f16)v1.z; hv[7] = (f16)v1.w;
            } else {
                f16x8 s8 = *(const f16x8*)(U + (size_t)gr * DIN + k8);
                float sf[8], g[8];
#pragma unroll
                for (int q = 0; q < 8; ++q) {
                    sf[q] = (float)s8[q];
                    if (MODE == M_SHARP_RELU) sf[q] = fmaxf(sf[q], 0.f);
                    g[q] = 0.f;
                }
                int e = offs[gr], e1 = offs[gr + 1];
                if (e < e1) {
                    const int last = e1 - 1;
                    for (; e < e1; e += 4) {
                        // clamped indices: tail lanes re-load the last edge's row
                        // (same cacheline -> L1-hit), accumulation predicated.
                        int i1 = (e + 1 < last) ? e + 1 : last;
                        int i2 = (e + 2 < last) ? e + 2 : last;
                        int i3 = (e + 3 < last) ? e + 3 : last;
                        int r0 = srcv[e], r1 = srcv[i1], r2 = srcv[i2], r3 = srcv[i3];
                        f16x8 t0 = *(const f16x8*)(U + (size_t)r0 * DIN + k8);
                        f16x8 t1 = *(const f16x8*)(U + (size_t)r1 * DIN + k8);
                        f16x8 t2 = *(const f16x8*)(U + (size_t)r2 * DIN + k8);
                        f16x8 t3 = *(const f16x8*)(U + (size_t)r3 * DIN + k8);
                        bool m1 = (e + 1 < e1), m2 = (e + 2 < e1), m3 = (e + 3 < e1);
#pragma unroll
                        for (int q = 0; q < 8; ++q) {
                            float a0 = (float)t0[q];
                            float a1 = (float)t1[q];
                            float a2 = (float)t2[q];
                            float a3 = (float)t3[q];
                            if (MODE == M_SHARP_RELU) {
                                a0 = fmaxf(a0, 0.f); a1 = fmaxf(a1, 0.f);
                                a2 = fmaxf(a2, 0.f); a3 = fmaxf(a3, 0.f);
                            }
                            a1 = m1 ? a1 : 0.f;
                            a2 = m2 ? a2 : 0.f;
                            a3 = m3 ? a3 : 0.f;
                            g[q] += (a0 + a1) + (a2 + a3);
                        }
                    }
                }
                float dv = gdinv[gr];
#pragma unroll
                for (int q = 0; q < 8; ++q) {
                    float v;
                    if (MODE == M_SMOOTH) {
                        v = fmaf(dv, g[q] + sf[q], gbias[k8 + q]);
                        v = fmaxf(v, 0.f);
                    } else {
                        v = dv * (2.f * sf[q] - g[q]);
                    }
                    hv[q] = (f16)v;
                }
            }
        }
        *(f16x8*)(Asm + (size_t)r * LDA + j * 16) = hv;
    }

    // ---- k-chunk loop: stage W chunk in LDS, MFMA from LDS ----
    for (int kc = 0; kc < NKC; ++kc) {
        const int kofs = kc * 32;
        if (kc > 0) __syncthreads();             // protect W buffer reuse
        for (int i = threadIdx.x; i < DOUT * 4; i += THREADS) {
            int c = i / 4, j = i % 4;
            f16x8 h8 = {0, 0, 0, 0, 0, 0, 0, 0}, l8 = {0, 0, 0, 0, 0, 0, 0, 0};
            if (kofs + j * 8 < DIN) {
                h8 = *(const f16x8*)(Wth + (size_t)c * DIN + kofs + j * 8);
                l8 = *(const f16x8*)(Wtl + (size_t)c * DIN + kofs + j * 8);
            }
            *(f16x8*)(Wh + (size_t)c * LDW + j * 16) = h8;
            *(f16x8*)(Wl + (size_t)c * LDW + j * 16) = l8;
        }
        __syncthreads();

        f16x8 a = *(const f16x8*)(Asm + (size_t)(wave * 16 + l15) * LDA + kc * 64 + lhi * 16);
#pragma unroll
        for (int t = 0; t < NT; ++t) {
            f16x8 bh = *(const f16x8*)(Wh + (size_t)(t * 16 + l15) * LDW + lhi * 16);
            f16x8 bl = *(const f16x8*)(Wl + (size_t)(t * 16 + l15) * LDW + lhi * 16);
            acc[t] = __builtin_amdgcn_mfma_f32_16x16x32_f16(a, bh, acc[t], 0, 0, 0);
            acc[t] = __builtin_amdgcn_mfma_f32_16x16x32_f16(a, bl, acc[t], 0, 0, 0);
        }
    }

    // ---- epilogue: C/D layout col=l&15, row=(l>>4)*4+r ----
    const int rbase = row0 + wave * 16 + (lhi << 2);
    float rsv[4]; int om[4];
#pragma unroll
    for (int r = 0; r < 4; ++r) {
        int row = rbase + r;
        bool ok = row < n;
        rsv[r] = (SCALE_ROW && ok) ? rs[row] : 1.0f;
        om[r] = ok ? (OUT_PERM ? map[row] : row) : -1;
    }
#pragma unroll
    for (int t = 0; t < NT; ++t) {
        int colb = t * 16 + l15;
        float b = ADD_BIAS ? bias[colb] : 0.f;
#pragma unroll
        for (int r = 0; r < 4; ++r) {
            if (om[r] < 0) continue;
            float v = acc[t][r] + b;
            if (RELU_OUT) v = fmaxf(v, 0.f);
            if (SCALE_ROW) v *= rsv[r];
            if (OUT_F32) outf[(size_t)om[r] * DOUT + colb] = v;
            else         outh[(size_t)om[r] * DOUT + colb] = (f16)v;
        }
    }
}

// ---------------- standalone smooth gather d=16, f16 -> f16 (L3->L4 boundary) ----------------
// Z' = ps[c] * ( dinv[c]*(Σ u[src] + u[c]) + bias ) — batch-4 clamped predicated walk.

__global__ __launch_bounds__(256) void gather16(
        const f16* __restrict__ u, const int* __restrict__ offs,
        const int* __restrict__ src, const float* __restrict__ dinv,
        const float* __restrict__ ps, const float* __restrict__ bias,
        f16* __restrict__ out, int n) {
    int idx = blockIdx.x * blockDim.x + threadIdx.x;
    int node = idx >> 1;
    if (node >= n) return;
    int d8 = (idx & 1) * 8;

    f16x8 s8 = *(const f16x8*)(u + (size_t)node * 16 + d8);
    float g[8];
#pragma unroll
    for (int q = 0; q < 8; ++q) g[q] = 0.f;
    int e = offs[node], e1 = offs[node + 1];
    if (e < e1) {
        const int last = e1 - 1;
        for (; e < e1; e += 4) {
            int i1 = (e + 1 < last) ? e + 1 : last;
            int i2 = (e + 2 < last) ? e + 2 : last;
            int i3 = (e + 3 < last) ? e + 3 : last;
            int r0 = src[e], r1 = src[i1], r2 = src[i2], r3 = src[i3];
            f16x8 t0 = *(const f16x8*)(u + (size_t)r0 * 16 + d8);
            f16x8 t1 = *(const f16x8*)(u + (size_t)r1 * 16 + d8);
            f16x8 t2 = *(const f16x8*)(u + (size_t)r2 * 16 + d8);
            f16x8 t3 = *(const f16x8*)(u + (size_t)r3 * 16 + d8);
            bool m1 = (e + 1 < e1), m2 = (e + 2 < e1), m3 = (e + 3 < e1);
#pragma unroll
            for (int q = 0; q < 8; ++q) {
                float a0 = (float)t0[q];
                float a1 = m1 ? (float)t1[q] : 0.f;
                float a2 = m2 ? (float)t2[q] : 0.f;
                float a3 = m3 ? (float)t3[q] : 0.f;
                g[q] += (a0 + a1) + (a2 + a3);
            }
        }
    }
    float dv = dinv[node], p = ps[node];
    f16x8 o;
#pragma unroll
    for (int q = 0; q < 8; ++q) {
        float v = p * (fmaf(dv, g[q] + (float)s8[q], bias[d8 + q]));
        o[q] = (f16)v;
    }
    *(f16x8*)(out + (size_t)node * 16 + d8) = o;
}

// ---------------- host orchestration ----------------

extern "C" void kernel_launch(void* const* d_in, const int* in_sizes, int n_in,
                              void* d_out, int out_size, void* d_ws, size_t ws_size,
                              hipStream_t stream) {
    const int T = 128;
    const int n = in_sizes[0] / T;        // 100000
    const int E = in_sizes[1] / 2;        // 600000

    const float* x   = (const float*)d_in[0];
    const int* eidx  = (const int*)d_in[1];
    const int* row   = eidx;
    const int* col   = eidx + E;
    const float* We1 = (const float*)d_in[2];
    const float* be1 = (const float*)d_in[3];
    const float* We2 = (const float*)d_in[4];
    const float* be2 = (const float*)d_in[5];
    const float* We3 = (const float*)d_in[6];
    const float* be3 = (const float*)d_in[7];
    const float* Wd1 = (const float*)d_in[8];
    const float* bd1 = (const float*)d_in[9];
    const float* Wd2 = (const float*)d_in[10];
    const float* bd2 = (const float*)d_in[11];
    const float* Wd3 = (const float*)d_in[12];
    const float* bd3 = (const float*)d_in[13];
    float* out = (float*)d_out;

    // workspace layout (all 16B aligned)
    char* base = (char*)d_ws;
    int*   deg      = (int*)base;   base += (size_t)n * 4;
    int*   offs     = (int*)base;   base += (size_t)(n + 4) * 4;
    int*   cursor   = (int*)base;   base += (size_t)(n + 4) * 4;
    int*   bhist    = (int*)base;   base += (size_t)512 * NBINS * 4;
    int*   bintot   = (int*)base;   base += (size_t)NBINS * 4;
    int*   binbase  = (int*)base;   base += (size_t)NBINS * 4;
    int*   edgebase = (int*)base;   base += (size_t)NBINS * 4;
    int*   order    = (int*)base;   base += (size_t)n * 4;
    int*   slotof   = (int*)base;   base += (size_t)n * 4;
    float* dinv_s   = (float*)base; base += (size_t)n * 4;
    float* dinv_h   = (float*)base; base += (size_t)n * 4;
    int*   src      = (int*)base;   base += (size_t)E * 4;
    f16*   wt_hi    = (f16*)base;   base += (size_t)21504 * 2 + 64;
    f16*   wt_lo    = (f16*)base;   base += (size_t)21504 * 2 + 64;
    f16*   bufA     = (f16*)base;   base += (size_t)n * 64 * 2;
    f16*   bufB     = (f16*)base;   base += (size_t)n * 64 * 2;
    (void)ws_size;

    const int BLK = 256;
    const int nhb = ceil_div(n, SCAN_BLK);

    // --- degrees ---
    zero_kernel<<<ceil_div(n, BLK), BLK, 0, stream>>>(deg, n);
    deg_kernel<<<ceil_div(E, BLK), BLK, 0, stream>>>(col, deg, E);

    // --- counting sort by degree + fused dinv/offs + CSR fill ---
    hist_kernel<<<nhb, SCAN_BLK, 0, stream>>>(deg, bhist, n);
    binscan_kernel<<<NBINS, 512, 0, stream>>>(bhist, bintot, nhb);
    base_scan_kernel<<<1, NBINS, 0, stream>>>(bintot, binbase, edgebase);
    place_kernel<<<nhb, SCAN_BLK, 0, stream>>>(
        deg, bhist, binbase, edgebase, order, slotof, dinv_s, dinv_h, offs, cursor, n, E);
    csr_fill_kernel<<<ceil_div(E, BLK), BLK, 0, stream>>>(row, col, slotof, cursor, src, E);

    // --- W transpose + f16 split (once per launch) ---
    WPtrs wp; wp.p[0] = We1; wp.p[1] = We2; wp.p[2] = We3;
    wp.p[3] = Wd1; wp.p[4] = Wd2; wp.p[5] = Wd3;
    wsplit_kernel<<<ceil_div(21504, BLK), BLK, 0, stream>>>(wp, wt_hi, wt_lo);

    const int ggrid = ceil_div(n, 128);

    // K1: u1 = dinv_s ⊙ (x[order] @ We1)                     [PLAIN]
    gemm_fused<128, 64, 8, M_PLAIN, false, false, true, true, false, false>
        <<<ggrid, 512, 0, stream>>>(
        x, nullptr, wt_hi + 0, wt_lo + 0, nullptr, nullptr, nullptr, nullptr,
        nullptr, dinv_s, order, nullptr, bufA, n);

    // K2: a1 = relu(dinv_s[c](Σu1+u1[c]) + be1); u2 = dinv_s ⊙ (a1 @ We2)   [SMOOTH]
    gemm_fused<64, 32, 8, M_SMOOTH, false, false, true, false, false, false>
        <<<ggrid, 512, 0, stream>>>(
        nullptr, bufA, wt_hi + 8192, wt_lo + 8192, be1, dinv_s, offs, src,
        nullptr, dinv_s, nullptr, nullptr, bufB, n);

    // K3: a2 = relu(dinv_s[c](Σu2+u2[c]) + be2); u3 = dinv_s ⊙ (a2 @ We3)   [SMOOTH]
    gemm_fused<32, 16, 8, M_SMOOTH, false, false, true, false, false, false>
        <<<ggrid, 512, 0, stream>>>(
        nullptr, bufB, wt_hi + 10240, wt_lo + 10240, be2, dinv_s, offs, src,
        nullptr, dinv_s, nullptr, nullptr, bufA, n);

    // K4: Z' = dinv_h ⊙ (dinv_s[c](Σu3+u3[c]) + be3)         [standalone gather]
    gather16<<<ceil_div(n * 2, BLK), BLK, 0, stream>>>(
        bufA, offs, src, dinv_s, dinv_h, be3, bufB, n);

    // K5: P4 = dinv_h[c](2 relu(Z'[c]) - Σ relu(Z'[src])); u4 = dinv_h ⊙ relu(P4@Wd1+bd1)
    gemm_fused<16, 32, 8, M_SHARP_RELU, true, true, true, false, false, false>
        <<<ggrid, 512, 0, stream>>>(
        nullptr, bufB, wt_hi + 10752, wt_lo + 10752, nullptr, dinv_h, offs, src,
        bd1, dinv_h, nullptr, nullptr, bufA, n);

    // K6: P5 = dinv_h[c](2 u4[c] - Σ u4); u5 = dinv_h ⊙ relu(P5@Wd2+bd2)    [SHARP]
    gemm_fused<32, 64, 8, M_SHARP, true, true, true, false, false, false>
        <<<ggrid, 512, 0, stream>>>(
        nullptr, bufA, wt_hi + 11264, wt_lo + 11264, nullptr, dinv_h, offs, src,
        bd2, dinv_h, nullptr, nullptr, bufB, n);

    // K7: P6 = dinv_h[c](2 u5[c] - Σ u5); out[order] = P6 @ Wd3 + bd3       [SHARP]
    gemm_fused<64, 128, 8, M_SHARP, true, false, false, false, true, true>
        <<<ggrid, 512, 0, stream>>>(
        nullptr, bufB, wt_hi + 13312, wt_lo + 13312, nullptr, dinv_h, offs, src,
        bd3, nullptr, order, out, nullptr, n);
}